// Round 2
// baseline (219.378 us; speedup 1.0000x reference)
//
#include <hip/hip_runtime.h>
#include <math.h>

// Problem constants
#define NTOT 4096        // H*W = 64*64
#define NBATCH 8
#define CIN 128
#define CK 64
#define CV 64
#define CO 128
#define BN_COUNT 32768.0f // B*H*W

// Workspace layout (float offsets). Total = 6,391,808 floats = 25.6 MB.
#define OFF_YQ    0ul
#define OFF_YK    2097152ul
#define OFF_V     4194304ul
#define OFF_STATS 6291456ul   // [which(2)][sum/sumsq(2)][64]
#define OFF_SC    6291712ul   // [which(2)][scale/shift(2)][64]
#define OFF_KV    6291968ul   // [8][64][64]
#define OFF_VSUM  6324736ul   // [8][64]
#define OFF_M     6325248ul   // [8][64][128]  (c,o)
#define OFF_D     6390784ul   // [8][128]

// ---------------------------------------------------------------------------
// Kernel 1: 1x1 conv as GEMM for q, k (Wk,bk) and v (Wv,bv).
// grid (64 col-chunks, 8 batch, 3 tensors), block 256.
// Block tile: 64 out-channels x 64 columns. Wave w handles o = w*16..w*16+15
// (wave-uniform -> W reads become scalar s_load), lane = column j.
// ---------------------------------------------------------------------------
__global__ __launch_bounds__(256) void gemm3_kernel(
    const float* __restrict__ Xq, const float* __restrict__ Xk, const float* __restrict__ Xv,
    const float* __restrict__ Wk, const float* __restrict__ bk,
    const float* __restrict__ Wv, const float* __restrict__ bv,
    float* __restrict__ Yq, float* __restrict__ Yk, float* __restrict__ Vv)
{
    const int chunk = blockIdx.x;
    const int b     = blockIdx.y;
    const int which = blockIdx.z;
    const float* X    = (which == 0) ? Xq : (which == 1) ? Xk : Xv;
    const float* W    = (which == 2) ? Wv : Wk;
    const float* bias = (which == 2) ? bv : bk;
    float* Y          = (which == 0) ? Yq : (which == 1) ? Yk : Vv;

    __shared__ float sX[CIN][64];   // 32 KB

    const int t = threadIdx.x;
    const int lane = t & 63;
    const int wu = __builtin_amdgcn_readfirstlane(t >> 6);  // wave id, uniform

    const int n0 = chunk * 64;
    const float* Xb = X + (size_t)b * (CIN * NTOT) + n0;

    // Stage X tile: 128 c x 64 j via float4 -> 2048 float4s, 8 per thread
#pragma unroll
    for (int r = 0; r < 8; ++r) {
        int idx4 = t + r * 256;           // 0..2047
        int c  = idx4 >> 4;               // 0..127
        int j4 = (idx4 & 15) << 2;        // 0..60
        float4 xv = *(const float4*)(Xb + (size_t)c * NTOT + j4);
        *(float4*)&sX[c][j4] = xv;
    }
    __syncthreads();

    const float* Wp = W + (size_t)wu * 16 * CIN;
    float acc[16];
#pragma unroll
    for (int ki = 0; ki < 16; ++ki) acc[ki] = 0.f;

#pragma unroll 8
    for (int c = 0; c < CIN; ++c) {
        float xv = sX[c][lane];
#pragma unroll
        for (int ki = 0; ki < 16; ++ki)
            acc[ki] += xv * Wp[ki * CIN + c];   // wave-uniform -> s_load
    }

    float* Yb = Y + (size_t)b * (CK * NTOT) + n0;
#pragma unroll
    for (int ki = 0; ki < 16; ++ki) {
        int o = wu * 16 + ki;
        Yb[(size_t)o * NTOT + lane] = acc[ki] + bias[o];
    }
}

// ---------------------------------------------------------------------------
// Kernel 2: BN batch stats (sum, sumsq) per channel for Yq and Yk.
// grid 128 = 2 tensors x 64 channels, block 256.
// ---------------------------------------------------------------------------
__global__ __launch_bounds__(256) void stats_kernel(
    const float* __restrict__ Yq, const float* __restrict__ Yk,
    float* __restrict__ stats)
{
    const int c     = blockIdx.x & 63;
    const int which = blockIdx.x >> 6;
    const float* Y = which ? Yk : Yq;

    float s = 0.f, ss = 0.f;
    for (int b = 0; b < NBATCH; ++b) {
        const float4* p = (const float4*)(Y + (size_t)b * (CK * NTOT) + (size_t)c * NTOT);
        for (int n4 = threadIdx.x; n4 < NTOT / 4; n4 += 256) {
            float4 v = p[n4];
            s  += v.x + v.y + v.z + v.w;
            ss += v.x * v.x + v.y * v.y + v.z * v.z + v.w * v.w;
        }
    }
#pragma unroll
    for (int off = 32; off > 0; off >>= 1) {
        s  += __shfl_down(s, off, 64);
        ss += __shfl_down(ss, off, 64);
    }
    __shared__ float red[8];
    int wave = threadIdx.x >> 6, lane = threadIdx.x & 63;
    if (lane == 0) { red[wave * 2] = s; red[wave * 2 + 1] = ss; }
    __syncthreads();
    if (threadIdx.x == 0) {
        float S  = red[0] + red[2] + red[4] + red[6];
        float SS = red[1] + red[3] + red[5] + red[7];
        stats[which * 128 + c]      = S;
        stats[which * 128 + 64 + c] = SS;
    }
}

// ---------------------------------------------------------------------------
// Kernel 3: per-channel BN scale/shift. 1 block, 128 threads.
// ---------------------------------------------------------------------------
__global__ void scale_kernel(const float* __restrict__ stats,
                             const float* __restrict__ gamma, const float* __restrict__ beta,
                             float* __restrict__ sc)
{
    int t = threadIdx.x;            // 0..127
    int which = t >> 6, c = t & 63;
    float S  = stats[which * 128 + c];
    float SS = stats[which * 128 + 64 + c];
    float mean = S * (1.f / BN_COUNT);
    float var  = SS * (1.f / BN_COUNT) - mean * mean;
    float scale = gamma[c] * rsqrtf(var + 1e-5f);
    float shift = beta[c] - mean * scale;
    sc[which * 128 + c]      = scale;
    sc[which * 128 + 64 + c] = shift;
}

// ---------------------------------------------------------------------------
// Kernel 4: KV[b,c,v] = sum_n kn[b,c,n]*V[b,v,n]; vsum[b,v] = sum_n V[b,v,n].
// kn = L2-normalized-over-c BN(Yk). grid (32 splits, 8 batch), block 256,
// each block does 2 chunks of 64 columns; atomicAdd partials.
// ---------------------------------------------------------------------------
__global__ __launch_bounds__(256) void kv_kernel(
    const float* __restrict__ Yk, const float* __restrict__ Vv,
    const float* __restrict__ sc, float* __restrict__ KV, float* __restrict__ vsum)
{
    const int s = blockIdx.x;
    const int b = blockIdx.y;
    __shared__ float sk[64][65];
    __shared__ float sv[64][65];
    __shared__ float rn[64];

    const int t = threadIdx.x;
    const int tc = t >> 4, tv = t & 15;
    float acc[4][4];
#pragma unroll
    for (int i = 0; i < 4; ++i)
#pragma unroll
        for (int k2 = 0; k2 < 4; ++k2) acc[i][k2] = 0.f;
    float vs = 0.f;

    const float* Ykb = Yk + (size_t)b * (CK * NTOT);
    const float* Vb  = Vv + (size_t)b * (CK * NTOT);

    for (int ch = 0; ch < 2; ++ch) {
        const int n0 = s * 128 + ch * 64;
        __syncthreads();   // protect prior iteration's LDS reads
#pragma unroll
        for (int r = 0; r < 4; ++r) {
            int idx4 = t + r * 256;
            int c  = idx4 >> 4;
            int j4 = (idx4 & 15) << 2;
            float4 kf = *(const float4*)(Ykb + (size_t)c * NTOT + n0 + j4);
            float4 vf = *(const float4*)(Vb  + (size_t)c * NTOT + n0 + j4);
            float scl = sc[128 + c], sh = sc[192 + c];
            sk[c][j4 + 0] = kf.x * scl + sh;
            sk[c][j4 + 1] = kf.y * scl + sh;
            sk[c][j4 + 2] = kf.z * scl + sh;
            sk[c][j4 + 3] = kf.w * scl + sh;
            sv[c][j4 + 0] = vf.x; sv[c][j4 + 1] = vf.y;
            sv[c][j4 + 2] = vf.z; sv[c][j4 + 3] = vf.w;
        }
        __syncthreads();
        if (t < 64) {
            float ssum = 0.f;
#pragma unroll 8
            for (int c = 0; c < 64; ++c) { float x = sk[c][t]; ssum += x * x; }
            rn[t] = 1.f / (sqrtf(ssum) + 1e-7f);
        }
        __syncthreads();
#pragma unroll
        for (int r = 0; r < 16; ++r) {
            int idx = t + r * 256;
            sk[idx >> 6][idx & 63] *= rn[idx & 63];
        }
        __syncthreads();
#pragma unroll 4
        for (int j = 0; j < 64; ++j) {
            float a[4], bb[4];
#pragma unroll
            for (int i = 0; i < 4; ++i) a[i]  = sk[tc * 4 + i][j];
#pragma unroll
            for (int i = 0; i < 4; ++i) bb[i] = sv[tv * 4 + i][j];
#pragma unroll
            for (int i = 0; i < 4; ++i)
#pragma unroll
                for (int k2 = 0; k2 < 4; ++k2) acc[i][k2] += a[i] * bb[k2];
        }
        if (t < 64) {
            float x = 0.f;
#pragma unroll 8
            for (int j = 0; j < 64; ++j) x += sv[t][j];
            vs += x;
        }
    }
    float* KVb = KV + b * (CK * CV);
#pragma unroll
    for (int i = 0; i < 4; ++i)
#pragma unroll
        for (int k2 = 0; k2 < 4; ++k2)
            atomicAdd(&KVb[(tc * 4 + i) * CV + tv * 4 + k2], acc[i][k2]);
    if (t < 64) atomicAdd(&vsum[b * CV + t], vs);
}

// ---------------------------------------------------------------------------
// Kernel 5: M[b,c,o] = sum_v KV[b,c,v]*Ww[o,v];  d[b,o] = bw[o] + sum_v Ww[o,v]*vsum[b,v]
// grid 8 (batch), block 256.
// ---------------------------------------------------------------------------
__global__ __launch_bounds__(256) void m_kernel(
    const float* __restrict__ KV, const float* __restrict__ vsum,
    const float* __restrict__ Ww, const float* __restrict__ bw,
    float* __restrict__ M, float* __restrict__ d)
{
    const int b = blockIdx.x;
    __shared__ float sKV[64][65];
    __shared__ float sWw[128][65];
    __shared__ float svs[64];
    const int t = threadIdx.x;

#pragma unroll
    for (int r = 0; r < 16; ++r) {
        int idx = t + r * 256;                       // 0..4095
        sKV[idx >> 6][idx & 63] = KV[b * (CK * CV) + idx];
    }
#pragma unroll
    for (int r = 0; r < 32; ++r) {
        int idx = t + r * 256;                       // 0..8191
        sWw[idx >> 6][idx & 63] = Ww[idx];
    }
    if (t < 64) svs[t] = vsum[b * CV + t];
    __syncthreads();

#pragma unroll
    for (int r = 0; r < 32; ++r) {
        int idx = t + r * 256;
        int c = idx >> 7, o = idx & 127;
        float acc = 0.f;
#pragma unroll 16
        for (int v = 0; v < 64; ++v) acc += sKV[c][v] * sWw[o][v];
        M[(size_t)b * (CK * CO) + idx] = acc;
    }
    if (t < 128) {
        float acc = bw[t];
#pragma unroll 16
        for (int v = 0; v < 64; ++v) acc += sWw[t][v] * svs[v];
        d[b * CO + t] = acc;
    }
}

// ---------------------------------------------------------------------------
// Kernel 6: out[b,o,n] = d[b,o] + sum_c qn[b,c,n] * M[b,c,o]
// qn = L2-normalized-over-c BN(Yq). grid (64 col-chunks, 8 batch), block 256.
// Thread tile: 4 cols x 8 out-channels (float4 LDS reads, VALU-bound).
// ---------------------------------------------------------------------------
__global__ __launch_bounds__(256) void out_kernel(
    const float* __restrict__ Yq, const float* __restrict__ sc,
    const float* __restrict__ M, const float* __restrict__ d,
    float* __restrict__ out)
{
    const int chunk = blockIdx.x;
    const int b     = blockIdx.y;
    __shared__ float sM[CK * CO];    // [c][o] flat, 32 KB
    __shared__ float sq[64][68];     // padded, float4-aligned rows
    __shared__ float rn[64];
    __shared__ float sd[CO];

    const int t = threadIdx.x;
    const int n0 = chunk * 64;

#pragma unroll
    for (int r = 0; r < 8; ++r) {
        int idx4 = t + r * 256;
        ((float4*)sM)[idx4] = ((const float4*)(M + (size_t)b * (CK * CO)))[idx4];
    }
    if (t < CO) sd[t] = d[b * CO + t];

    const float* Yb = Yq + (size_t)b * (CK * NTOT) + n0;
#pragma unroll
    for (int r = 0; r < 4; ++r) {
        int idx4 = t + r * 256;
        int c  = idx4 >> 4;
        int j4 = (idx4 & 15) << 2;
        float4 xv = *(const float4*)(Yb + (size_t)c * NTOT + j4);
        float scl = sc[c], sh = sc[64 + c];
        sq[c][j4 + 0] = xv.x * scl + sh;
        sq[c][j4 + 1] = xv.y * scl + sh;
        sq[c][j4 + 2] = xv.z * scl + sh;
        sq[c][j4 + 3] = xv.w * scl + sh;
    }
    __syncthreads();
    if (t < 64) {
        float ssum = 0.f;
#pragma unroll 8
        for (int c = 0; c < 64; ++c) { float x = sq[c][t]; ssum += x * x; }
        rn[t] = 1.f / (sqrtf(ssum) + 1e-7f);
    }
    __syncthreads();
#pragma unroll
    for (int r = 0; r < 16; ++r) {
        int idx = t + r * 256;
        sq[idx >> 6][idx & 63] *= rn[idx & 63];
    }
    __syncthreads();

    const int j0 = (t & 15) << 2;       // 4 columns
    const int o0 = (t >> 4) << 3;       // 8 out-channels
    float acc[4][8];
#pragma unroll
    for (int jj = 0; jj < 4; ++jj)
#pragma unroll
        for (int oo = 0; oo < 8; ++oo) acc[jj][oo] = sd[o0 + oo];

#pragma unroll 4
    for (int c = 0; c < 64; ++c) {
        float4 qv = *(const float4*)&sq[c][j0];
        float4 m0 = *(const float4*)&sM[c * CO + o0];
        float4 m1 = *(const float4*)&sM[c * CO + o0 + 4];
        float aq[4] = {qv.x, qv.y, qv.z, qv.w};
        float am[8] = {m0.x, m0.y, m0.z, m0.w, m1.x, m1.y, m1.z, m1.w};
#pragma unroll
        for (int jj = 0; jj < 4; ++jj)
#pragma unroll
            for (int oo = 0; oo < 8; ++oo) acc[jj][oo] += aq[jj] * am[oo];
    }

    float* outb = out + (size_t)b * (CO * NTOT) + n0;
#pragma unroll
    for (int oo = 0; oo < 8; ++oo) {
        float4 st = make_float4(acc[0][oo], acc[1][oo], acc[2][oo], acc[3][oo]);
        *(float4*)&outb[(size_t)(o0 + oo) * NTOT + j0] = st;
    }
}

// ---------------------------------------------------------------------------
extern "C" void kernel_launch(void* const* d_in, const int* in_sizes, int n_in,
                              void* d_out, int out_size, void* d_ws, size_t ws_size,
                              hipStream_t stream) {
    (void)in_sizes; (void)n_in; (void)out_size; (void)ws_size;
    const float* q     = (const float*)d_in[0];
    const float* k     = (const float*)d_in[1];
    const float* v     = (const float*)d_in[2];
    const float* Wk    = (const float*)d_in[3];
    const float* bk    = (const float*)d_in[4];
    const float* gamma = (const float*)d_in[5];
    const float* beta  = (const float*)d_in[6];
    const float* Wv    = (const float*)d_in[7];
    const float* bv    = (const float*)d_in[8];
    const float* Ww    = (const float*)d_in[9];
    const float* bw    = (const float*)d_in[10];
    float* out = (float*)d_out;
    float* ws  = (float*)d_ws;

    float* Yq    = ws + OFF_YQ;
    float* Yk    = ws + OFF_YK;
    float* Vv    = ws + OFF_V;
    float* stats = ws + OFF_STATS;
    float* sc    = ws + OFF_SC;
    float* KV    = ws + OFF_KV;
    float* vsum  = ws + OFF_VSUM;
    float* M     = ws + OFF_M;
    float* dd    = ws + OFF_D;

    // zero the accumulated buffers (ws is re-poisoned before every call)
    hipMemsetAsync(KV, 0, (CK * CV * NBATCH + CV * NBATCH) * sizeof(float), stream);

    gemm3_kernel<<<dim3(64, NBATCH, 3), 256, 0, stream>>>(q, k, v, Wk, bk, Wv, bv, Yq, Yk, Vv);
    stats_kernel<<<128, 256, 0, stream>>>(Yq, Yk, stats);
    scale_kernel<<<1, 128, 0, stream>>>(stats, gamma, beta, sc);
    kv_kernel<<<dim3(32, NBATCH), 256, 0, stream>>>(Yk, Vv, sc, KV, vsum);
    m_kernel<<<NBATCH, 256, 0, stream>>>(KV, vsum, Ww, bw, M, dd);
    out_kernel<<<dim3(64, NBATCH), 256, 0, stream>>>(Yq, sc, M, dd, out);
}